// Round 1
// baseline (4126.902 us; speedup 1.0000x reference)
//
#include <hip/hip_runtime.h>
#include <cmath>

#define B_   8
#define L_   4096
#define D_   1024
#define NQK_ 2048
#define M_   32768   // B_*L_

// ---------------------------------------------------------------------------
// fp32 GEMM: C[M,N] = A[M,K] @ B[K,N]; mode 1 epilogue adds H[b,cid[m],:] + bres
// 128x128 tile, BK=32, 256 threads, 8x8 microtile per thread.
// ---------------------------------------------------------------------------
__global__ __launch_bounds__(256) void gemm_fp32(
    const float* __restrict__ A, const float* __restrict__ Bm,
    float* __restrict__ C, int N, int K, int mode,
    const float* __restrict__ Hs, const int* __restrict__ cid,
    const float* __restrict__ bres)
{
  __shared__ float As[32 * 132];   // transposed [k][m], pad 132 keeps 16B align
  __shared__ float Bs[32 * 128];   // [k][n]
  const int tid = threadIdx.x;
  const int tr = tid >> 4, tc = tid & 15;
  const int m0 = blockIdx.y * 128, n0 = blockIdx.x * 128;

  float acc[8][8];
#pragma unroll
  for (int i = 0; i < 8; i++)
#pragma unroll
    for (int j = 0; j < 8; j++) acc[i][j] = 0.f;

  for (int kt = 0; kt < K; kt += 32) {
    __syncthreads();
#pragma unroll
    for (int i = 0; i < 4; i++) {           // A tile 128x32, transpose into LDS
      int s = i * 256 + tid;
      int r = s >> 3, kc = (s & 7) << 2;
      float4 v = *(const float4*)(A + (size_t)(m0 + r) * K + (kt + kc));
      As[(kc + 0) * 132 + r] = v.x;
      As[(kc + 1) * 132 + r] = v.y;
      As[(kc + 2) * 132 + r] = v.z;
      As[(kc + 3) * 132 + r] = v.w;
    }
#pragma unroll
    for (int i = 0; i < 4; i++) {           // B tile 32x128
      int s = i * 256 + tid;
      int r = s >> 5, nc = (s & 31) << 2;
      *(float4*)(Bs + r * 128 + nc) =
          *(const float4*)(Bm + (size_t)(kt + r) * N + (n0 + nc));
    }
    __syncthreads();
#pragma unroll
    for (int k = 0; k < 32; k++) {
      float a[8], b[8];
      *(float4*)(a)     = *(const float4*)(As + k * 132 + tr * 8);
      *(float4*)(a + 4) = *(const float4*)(As + k * 132 + tr * 8 + 4);
      *(float4*)(b)     = *(const float4*)(Bs + k * 128 + tc * 4);
      *(float4*)(b + 4) = *(const float4*)(Bs + k * 128 + tc * 4 + 64);
#pragma unroll
      for (int i = 0; i < 8; i++)
#pragma unroll
        for (int j = 0; j < 8; j++)
          acc[i][j] = fmaf(a[i], b[j], acc[i][j]);
    }
  }

#pragma unroll
  for (int i = 0; i < 8; i++) {
    int gm = m0 + tr * 8 + i;
    float* crow = C + (size_t)gm * N + n0;
    float o[8];
#pragma unroll
    for (int j = 0; j < 8; j++) o[j] = acc[i][j];
    if (mode == 1) {
      int c = cid[gm];                       // chunk id of this row
      const float* hrow = Hs + (size_t)((gm & ~4095) + c) * 1024 + n0;
#pragma unroll
      for (int j = 0; j < 4; j++) {
        o[j]     += hrow[tc * 4 + j]      + bres[n0 + tc * 4 + j];
        o[j + 4] += hrow[64 + tc * 4 + j] + bres[n0 + 64 + tc * 4 + j];
      }
    }
    *(float4*)(crow + tc * 4)      = make_float4(o[0], o[1], o[2], o[3]);
    *(float4*)(crow + 64 + tc * 4) = make_float4(o[4], o[5], o[6], o[7]);
  }
}

// ---------------------------------------------------------------------------
// probs: one wave per position. q = C1[l, 0:1024], ks = C1[l-1, 1024:2048]
// (start_key at l==0). probs = 0.5*(1 - cos).
// ---------------------------------------------------------------------------
__global__ __launch_bounds__(256) void probs_kernel(
    const float* __restrict__ C1, const float* __restrict__ sk,
    float* __restrict__ probs)
{
  int gt = blockIdx.x * 256 + threadIdx.x;
  int wid = gt >> 6;
  int lane = threadIdx.x & 63;
  const float* q = C1 + (size_t)wid * 2048;
  const float* ks = ((wid & 4095) == 0) ? sk
                                        : (C1 + (size_t)(wid - 1) * 2048 + 1024);
  float dq = 0.f, nq = 0.f, nk = 0.f;
  int e0 = lane * 16;
#pragma unroll
  for (int j = 0; j < 4; j++) {
    float4 qv = *(const float4*)(q + e0 + j * 4);
    float4 kv = *(const float4*)(ks + e0 + j * 4);
    dq += qv.x * kv.x + qv.y * kv.y + qv.z * kv.z + qv.w * kv.w;
    nq += qv.x * qv.x + qv.y * qv.y + qv.z * qv.z + qv.w * qv.w;
    nk += kv.x * kv.x + kv.y * kv.y + kv.z * kv.z + kv.w * kv.w;
  }
#pragma unroll
  for (int off = 32; off > 0; off >>= 1) {
    dq += __shfl_down(dq, off);
    nq += __shfl_down(nq, off);
    nk += __shfl_down(nk, off);
  }
  if (lane == 0)
    probs[wid] = 0.5f * (1.f - dq / fmaxf(sqrtf(nq) * sqrtf(nk), 1e-8f));
}

// ---------------------------------------------------------------------------
// fp64 re-check of positions with |cos| < 1e-4: boundary sign must match the
// fp32 numpy reference; near-threshold rounding would flip chunk structure.
// ---------------------------------------------------------------------------
__global__ __launch_bounds__(256) void recheck_kernel(
    const float* __restrict__ tok, const float* __restrict__ Wqk,
    const float* __restrict__ sk, float* __restrict__ probs)
{
  __shared__ double red[3][4];
  int t = threadIdx.x;
  for (int pi = 0; pi < 128; pi++) {
    int gm = blockIdx.x * 128 + pi;
    float cosv = 1.f - 2.f * probs[gm];
    if (fabsf(cosv) >= 1e-4f) continue;     // block-uniform branch
    int l = gm & 4095;
    const float* trow = tok + (size_t)gm * 1024;
    const float* prow = tok + (size_t)(gm - 1) * 1024;
    double dq = 0, nq = 0, nk = 0;
    for (int i = 0; i < 4; i++) {
      int e = t + i * 256;
      double qe = 0, ke = 0;
      for (int d = 0; d < 1024; d++)
        qe += (double)trow[d] * (double)Wqk[(size_t)d * 2048 + e];
      if (l == 0) ke = (double)sk[e];
      else
        for (int d = 0; d < 1024; d++)
          ke += (double)prow[d] * (double)Wqk[(size_t)d * 2048 + 1024 + e];
      dq += qe * ke; nq += qe * qe; nk += ke * ke;
    }
#pragma unroll
    for (int off = 32; off > 0; off >>= 1) {
      dq += __shfl_down(dq, off);
      nq += __shfl_down(nq, off);
      nk += __shfl_down(nk, off);
    }
    int w = t >> 6;
    if ((t & 63) == 0) { red[0][w] = dq; red[1][w] = nq; red[2][w] = nk; }
    __syncthreads();
    if (t == 0) {
      double DQ = red[0][0] + red[0][1] + red[0][2] + red[0][3];
      double NQ = red[1][0] + red[1][1] + red[1][2] + red[1][3];
      double NK = red[2][0] + red[2][1] + red[2][2] + red[2][3];
      double den = sqrt(NQ) * sqrt(NK);
      if (den < 1e-8) den = 1e-8;
      probs[gm] = (float)(0.5 * (1.0 - DQ / den));
    }
    __syncthreads();
  }
}

// ---------------------------------------------------------------------------
// meta: per batch row — boundary flags, inclusive cumsum -> chunk_id,
// compacted boundary pos/prob lists, num_chunks, per-batch aux value.
// ---------------------------------------------------------------------------
__global__ __launch_bounds__(256) void meta_kernel(
    const float* __restrict__ probs, int* __restrict__ cid,
    int* __restrict__ pos, float* __restrict__ cprob,
    int* __restrict__ numC, float* __restrict__ auxv)
{
  __shared__ int   sc[256];
  __shared__ float psh[256];
  int b = blockIdx.x, t = threadIdx.x;
  const float* pr = probs + b * 4096;
  int base = t * 16;
  float pv[16]; int loc[16]; bool bd[16];
  int cnt = 0; float ps = 0.f;
#pragma unroll
  for (int i = 0; i < 16; i++) {
    float p = pr[base + i];
    pv[i] = p; ps += p;
    bool bb = (base + i == 0) || (p > 0.5f);
    bd[i] = bb; cnt += bb ? 1 : 0; loc[i] = cnt;
  }
  sc[t] = cnt; psh[t] = ps;
  __syncthreads();
  for (int off = 1; off < 256; off <<= 1) {   // Hillis-Steele inclusive scan
    int add = (t >= off) ? sc[t - off] : 0;
    __syncthreads();
    sc[t] += add;
    __syncthreads();
  }
  int excl = sc[t] - cnt;
#pragma unroll
  for (int i = 0; i < 16; i++) {
    int c = excl + loc[i] - 1;
    cid[b * 4096 + base + i] = c;
    if (bd[i]) { pos[b * 4096 + c] = base + i; cprob[b * 4096 + c] = pv[i]; }
  }
  int total = sc[255];
  for (int off = 128; off > 0; off >>= 1) {
    if (t < off) psh[t] += psh[t + off];
    __syncthreads();
  }
  if (t == 0) {
    numC[b] = total;
    float F = (float)total / 4096.f;
    float G = psh[0] / 4096.f;
    auxv[b] = 1.2f * (5.f * F * G + (1.f - F) * (1.f - G));
  }
}

__global__ void aux_final(const float* __restrict__ auxv, float* __restrict__ out2)
{
  if (threadIdx.x == 0) {
    float s = 0.f;
    for (int i = 0; i < 8; i++) s += auxv[i];
    out2[0] = s * (0.03f / 8.f);
  }
}

// ---------------------------------------------------------------------------
// downsampled[b,c,:] = p_c * tokens[b,pos_c,:]; zero for pad slots.
// ---------------------------------------------------------------------------
__global__ __launch_bounds__(256) void down_kernel(
    const float* __restrict__ tok, const int* __restrict__ pos,
    const float* __restrict__ cprob, const int* __restrict__ numC,
    float* __restrict__ out0)
{
  int blk = blockIdx.x;
  int b = blk >> 12, slot = blk & 4095;
  float4 v = make_float4(0.f, 0.f, 0.f, 0.f);
  if (slot < numC[b]) {
    int l = pos[blk];
    float p = cprob[blk];
    float4 tv = *(const float4*)(tok + (size_t)((b << 12) + l) * 1024 + threadIdx.x * 4);
    v = make_float4(p * tv.x, p * tv.y, p * tv.z, p * tv.w);
  }
  *(float4*)(out0 + (size_t)blk * 1024 + threadIdx.x * 4) = v;
}

// ---------------------------------------------------------------------------
// Segmented gated scan: h_c = (1-p_c) h_{c-1} + downsampled_c.
// Every natural boundary has p>0.5 => gate<0.5 => 64-step warm-up is exact
// to <2^-64. Segment 0 starts exactly at h_{-1}=0.
// ---------------------------------------------------------------------------
__global__ __launch_bounds__(256) void scanH_kernel(
    const float* __restrict__ out0, const float* __restrict__ cprob,
    const int* __restrict__ numC, float* __restrict__ H)
{
  int seg = blockIdx.x, b = blockIdx.y;
  int nc = numC[b];
  int cs = seg << 8;
  if (cs >= nc) return;
  int ce = min(cs + 256, nc);
  int c0 = (seg == 0) ? 0 : cs - 64;
  int off = threadIdx.x * 4;
  float hx = 0.f, hy = 0.f, hz = 0.f, hw = 0.f;
  int c = c0;
  for (; c < cs; c++) {                       // warm-up, no store
    float g = 1.f - cprob[(b << 12) + c];
    float4 x = *(const float4*)(out0 + (size_t)((b << 12) + c) * 1024 + off);
    hx = fmaf(g, hx, x.x); hy = fmaf(g, hy, x.y);
    hz = fmaf(g, hz, x.z); hw = fmaf(g, hw, x.w);
  }
  for (; c < ce; c++) {
    float g = 1.f - cprob[(b << 12) + c];
    float4 x = *(const float4*)(out0 + (size_t)((b << 12) + c) * 1024 + off);
    hx = fmaf(g, hx, x.x); hy = fmaf(g, hy, x.y);
    hz = fmaf(g, hz, x.z); hw = fmaf(g, hw, x.w);
    *(float4*)(H + (size_t)((b << 12) + c) * 1024 + off) = make_float4(hx, hy, hz, hw);
  }
}

// ---------------------------------------------------------------------------
extern "C" void kernel_launch(void* const* d_in, const int* in_sizes, int n_in,
                              void* d_out, int out_size, void* d_ws, size_t ws_size,
                              hipStream_t stream)
{
  const float* tokens = (const float*)d_in[0];   // [8,4096,1024]
  const float* Wqk    = (const float*)d_in[1];   // [1024,2048]
  const float* sk     = (const float*)d_in[2];   // [1024]
  const float* Wres   = (const float*)d_in[3];   // [1024,1024]
  const float* bres   = (const float*)d_in[4];   // [1024]

  float* out0 = (float*)d_out;                   // downsampled [8,4096,1024]
  float* out1 = out0 + (size_t)M_ * D_;          // ups         [8,4096,1024]
  float* out2 = out1 + (size_t)M_ * D_;          // weighted_aux scalar

  float* wsf  = (float*)d_ws;
  float* C1   = wsf;                             // [32768,2048] qk proj (268MB)
  float* Hbuf = wsf;                             // [8,4096,1024] aliases C1 (dead after probs)
  float* probs = wsf + (size_t)M_ * NQK_;        // [32768]
  int*   cidp  = (int*)(probs + M_);             // [32768]
  int*   posp  = (int*)(probs + 2 * (size_t)M_); // [32768]
  float* cprob = probs + 3 * (size_t)M_;         // [32768]
  int*   numC  = (int*)(probs + 4 * (size_t)M_); // [8]
  float* auxv  = (float*)(numC + 8);             // [8]

  // 1. qk projection (fp32 — boundary sign needs fp32 accuracy)
  gemm_fp32<<<dim3(16, 256), 256, 0, stream>>>(tokens, Wqk, C1, NQK_, D_, 0,
                                               nullptr, nullptr, nullptr);
  // 2. cosine -> probs
  probs_kernel<<<8192, 256, 0, stream>>>(C1, sk, probs);
  // 3. fp64 re-check of near-threshold positions
  recheck_kernel<<<256, 256, 0, stream>>>(tokens, Wqk, sk, probs);
  // 4. boundaries / chunk ids / compaction / aux
  meta_kernel<<<8, 256, 0, stream>>>(probs, cidp, posp, cprob, numC, auxv);
  aux_final<<<1, 64, 0, stream>>>(auxv, out2);
  // 5. downsampled output (also the scan input)
  down_kernel<<<M_, 256, 0, stream>>>(tokens, posp, cprob, numC, out0);
  // 6. segmented gated scan -> H (reuses C1 space)
  scanH_kernel<<<dim3(16, 8), 256, 0, stream>>>(out0, cprob, numC, Hbuf);
  // 7. ups = H[chunk_id] + tokens @ W_res + b_res (fused epilogue)
  gemm_fp32<<<dim3(8, 256), 256, 0, stream>>>(tokens, Wres, out1, D_, D_, 1,
                                              Hbuf, cidp, bres);
}

// Round 2
// 2636.859 us; speedup vs baseline: 1.5651x; 1.5651x over previous
//
#include <hip/hip_runtime.h>
#include <hip/hip_fp16.h>
#include <cmath>

typedef unsigned short u16;
typedef short v8s __attribute__((ext_vector_type(8)));
typedef float v4f __attribute__((ext_vector_type(4)));

#define B_   8
#define L_   4096
#define D_   1024
#define M_   32768

// ---------------------------------------------------------------------------
// fp32 -> bf16 hi/lo split (RN on both; lo = a - hi exact by Sterbenz)
// ---------------------------------------------------------------------------
__device__ __forceinline__ void split2(float a, u16& h, u16& l) {
  unsigned ab = __float_as_uint(a);
  unsigned hb = (ab + 0x8000u) & 0xFFFF0000u;
  float hf = __uint_as_float(hb);
  float lf = a - hf;
  h = (u16)(hb >> 16);
  l = (u16)((__float_as_uint(lf) + 0x8000u) >> 16);
}

// tokens [32768,1024] fp32 -> Th, Tl bf16 row-major
__global__ __launch_bounds__(256) void split_tok(const float* __restrict__ T,
    u16* __restrict__ Th, u16* __restrict__ Tl) {
  size_t id = (size_t)blockIdx.x * 256 + threadIdx.x;   // 4M threads
  size_t base = id * 8;
  float4 v0 = *(const float4*)(T + base);
  float4 v1 = *(const float4*)(T + base + 4);
  float a[8] = {v0.x, v0.y, v0.z, v0.w, v1.x, v1.y, v1.z, v1.w};
  u16 h[8], l[8];
#pragma unroll
  for (int j = 0; j < 8; j++) split2(a[j], h[j], l[j]);
  *(uint4*)(Th + base) = *(uint4*)h;
  *(uint4*)(Tl + base) = *(uint4*)l;
}

// W [1024,N] fp32 -> Wh,Wl transposed [N,1024] bf16. Coalesced reads along n.
__global__ __launch_bounds__(256) void split_wT(const float* __restrict__ W,
    int N, u16* __restrict__ Wh, u16* __restrict__ Wl) {
  int id = blockIdx.x * 256 + threadIdx.x;   // N*128 threads
  int n = id & (N - 1);
  int k0 = (id / N) * 8;
  float a[8];
#pragma unroll
  for (int j = 0; j < 8; j++) a[j] = W[(size_t)(k0 + j) * N + n];
  u16 h[8], l[8];
#pragma unroll
  for (int j = 0; j < 8; j++) split2(a[j], h[j], l[j]);
  *(uint4*)(Wh + (size_t)n * 1024 + k0) = *(uint4*)h;
  *(uint4*)(Wl + (size_t)n * 1024 + k0) = *(uint4*)l;
}

__device__ __forceinline__ void gll16(const void* g, void* l) {
  __builtin_amdgcn_global_load_lds(
      (const __attribute__((address_space(1))) void*)g,
      (__attribute__((address_space(3))) void*)l, 16, 0, 0);
}

// ---------------------------------------------------------------------------
// bf16x3 MFMA GEMM: C = A*B, A=[32768,1024] (hi/lo), B^T=[N,1024] (hi/lo).
// mode 0: store fp16 C. mode 1: fp32 store of acc + H[b,cid] + bres.
// 128x128 tile, BK=32, 4 waves (2x2 of 64x64), 16x16x32 MFMA, 3 products.
// global_load_lds staging with swizzle baked into per-lane global addresses.
// ---------------------------------------------------------------------------
__global__ __launch_bounds__(256) void gemm_mfma(
    const u16* __restrict__ Ah, const u16* __restrict__ Al,
    const u16* __restrict__ Bh, const u16* __restrict__ Bl,
    void* __restrict__ Cout, int N, int NTN, int mode,
    const float* __restrict__ Hs, const int* __restrict__ cid,
    const float* __restrict__ bres)
{
  __shared__ u16 lds4[4][4096];   // Ah,Al,Bh,Bl tiles: 128 rows x 32 bf16
  const int tid = threadIdx.x;
  const int lane = tid & 63, w = tid >> 6;
  const int q = lane >> 4, fr = lane & 15;
  const int wr = w >> 1, wc = w & 1;
  // XCD swizzle: all n-tiles of an m-row stay on one XCD (L2 reuse of A)
  int bid = blockIdx.x;
  int idx = bid >> 3, x = bid & 7;
  const int n0 = (idx % NTN) * 128;
  const int m0 = (x * 32 + idx / NTN) * 128;

  const u16* src = (w == 0) ? Ah : (w == 1) ? Al : (w == 2) ? Bh : Bl;
  const int rowbase = (w < 2) ? m0 : n0;

  v4f acc[4][4];
#pragma unroll
  for (int i = 0; i < 4; i++)
#pragma unroll
    for (int j = 0; j < 4; j++) acc[i][j] = (v4f)0.f;

  for (int kt = 0; kt < 32; kt++) {
    const u16* sk = src + kt * 32;
#pragma unroll
    for (int j = 0; j < 8; j++) {            // stage 8KB per wave
      int lam = j * 64 + lane;
      int mi = lam >> 2;
      int qq = (lam & 3) ^ ((lam >> 3) & 3); // chunk swizzle (2-way max)
      gll16(sk + (size_t)(rowbase + mi) * 1024 + qq * 8, &lds4[w][j * 512]);
    }
    __syncthreads();                         // drains vmcnt before reads
    v8s bh[4], bl[4];
#pragma unroll
    for (int nt = 0; nt < 4; nt++) {
      int r = wc * 64 + nt * 16 + fr;
      int off = r * 32 + ((q ^ ((r >> 1) & 3)) << 3);
      bh[nt] = *(const v8s*)&lds4[2][off];
      bl[nt] = *(const v8s*)&lds4[3][off];
    }
#pragma unroll
    for (int mt = 0; mt < 4; mt++) {
      int r = wr * 64 + mt * 16 + fr;
      int off = r * 32 + ((q ^ ((r >> 1) & 3)) << 3);
      v8s ah = *(const v8s*)&lds4[0][off];
      v8s al = *(const v8s*)&lds4[1][off];
#pragma unroll
      for (int nt = 0; nt < 4; nt++) {
        acc[mt][nt] = __builtin_amdgcn_mfma_f32_16x16x32_bf16(ah, bh[nt], acc[mt][nt], 0, 0, 0);
        acc[mt][nt] = __builtin_amdgcn_mfma_f32_16x16x32_bf16(al, bh[nt], acc[mt][nt], 0, 0, 0);
        acc[mt][nt] = __builtin_amdgcn_mfma_f32_16x16x32_bf16(ah, bl[nt], acc[mt][nt], 0, 0, 0);
      }
    }
    __syncthreads();                         // compute done before re-stage
  }

  if (mode == 0) {
    __half* C = (__half*)Cout;
#pragma unroll
    for (int mt = 0; mt < 4; mt++)
#pragma unroll
      for (int r = 0; r < 4; r++) {
        int grow = m0 + wr * 64 + mt * 16 + q * 4 + r;
        __half* crow = C + (size_t)grow * N + n0 + wc * 64 + fr;
#pragma unroll
        for (int nt = 0; nt < 4; nt++)
          crow[nt * 16] = __float2half(acc[mt][nt][r]);
      }
  } else {
    float* C = (float*)Cout;
#pragma unroll
    for (int mt = 0; mt < 4; mt++)
#pragma unroll
      for (int r = 0; r < 4; r++) {
        int grow = m0 + wr * 64 + mt * 16 + q * 4 + r;
        int b = grow >> 12;
        int cc = cid[grow];
        const float* hrow = Hs + (size_t)((b << 12) + cc) * 1024 + n0 + wc * 64 + fr;
        const float* brow = bres + n0 + wc * 64 + fr;
        float* crow = C + (size_t)grow * 1024 + n0 + wc * 64 + fr;
#pragma unroll
        for (int nt = 0; nt < 4; nt++)
          crow[nt * 16] = acc[mt][nt][r] + hrow[nt * 16] + brow[nt * 16];
      }
  }
}

// ---------------------------------------------------------------------------
// probs from fp16 C1: one wave per position.
// ---------------------------------------------------------------------------
__global__ __launch_bounds__(256) void probs_half(const __half* __restrict__ C1,
    const float* __restrict__ skey, float* __restrict__ probs)
{
  int gt = blockIdx.x * 256 + threadIdx.x;
  int wid = gt >> 6, lane = threadIdx.x & 63;
  float qv[16], kv[16];
  {
    const __half2* p2 = (const __half2*)(C1 + (size_t)wid * 2048 + lane * 16);
#pragma unroll
    for (int j = 0; j < 8; j++) {
      float2 f = __half22float2(p2[j]); qv[2 * j] = f.x; qv[2 * j + 1] = f.y;
    }
  }
  if ((wid & 4095) == 0) {
#pragma unroll
    for (int j = 0; j < 16; j++) kv[j] = skey[lane * 16 + j];
  } else {
    const __half2* p2 = (const __half2*)(C1 + (size_t)(wid - 1) * 2048 + 1024 + lane * 16);
#pragma unroll
    for (int j = 0; j < 8; j++) {
      float2 f = __half22float2(p2[j]); kv[2 * j] = f.x; kv[2 * j + 1] = f.y;
    }
  }
  float dq = 0.f, nq = 0.f, nk = 0.f;
#pragma unroll
  for (int j = 0; j < 16; j++) {
    dq += qv[j] * kv[j]; nq += qv[j] * qv[j]; nk += kv[j] * kv[j];
  }
#pragma unroll
  for (int off = 32; off > 0; off >>= 1) {
    dq += __shfl_down(dq, off);
    nq += __shfl_down(nq, off);
    nk += __shfl_down(nk, off);
  }
  if (lane == 0)
    probs[wid] = 0.5f * (1.f - dq / fmaxf(sqrtf(nq) * sqrtf(nk), 1e-8f));
}

// ---------------------------------------------------------------------------
// fp64 re-check of |cos| < 1e-4 positions (boundary-sign safety vs np fp32)
// ---------------------------------------------------------------------------
__global__ __launch_bounds__(256) void recheck_kernel(
    const float* __restrict__ tok, const float* __restrict__ Wqk,
    const float* __restrict__ sk, float* __restrict__ probs)
{
  __shared__ double red[3][4];
  int t = threadIdx.x;
  for (int pi = 0; pi < 128; pi++) {
    int gm = blockIdx.x * 128 + pi;
    float cosv = 1.f - 2.f * probs[gm];
    if (fabsf(cosv) >= 1e-4f) continue;     // block-uniform branch
    int l = gm & 4095;
    const float* trow = tok + (size_t)gm * 1024;
    const float* prow = tok + (size_t)(gm - 1) * 1024;
    double dq = 0, nq = 0, nk = 0;
    for (int i = 0; i < 4; i++) {
      int e = t + i * 256;
      double qe = 0, ke = 0;
      for (int d = 0; d < 1024; d++)
        qe += (double)trow[d] * (double)Wqk[(size_t)d * 2048 + e];
      if (l == 0) ke = (double)sk[e];
      else
        for (int d = 0; d < 1024; d++)
          ke += (double)prow[d] * (double)Wqk[(size_t)d * 2048 + 1024 + e];
      dq += qe * ke; nq += qe * qe; nk += ke * ke;
    }
#pragma unroll
    for (int off = 32; off > 0; off >>= 1) {
      dq += __shfl_down(dq, off);
      nq += __shfl_down(nq, off);
      nk += __shfl_down(nk, off);
    }
    int w = t >> 6;
    if ((t & 63) == 0) { red[0][w] = dq; red[1][w] = nq; red[2][w] = nk; }
    __syncthreads();
    if (t == 0) {
      double DQ = red[0][0] + red[0][1] + red[0][2] + red[0][3];
      double NQ = red[1][0] + red[1][1] + red[1][2] + red[1][3];
      double NK = red[2][0] + red[2][1] + red[2][2] + red[2][3];
      double den = sqrt(NQ) * sqrt(NK);
      if (den < 1e-8) den = 1e-8;
      probs[gm] = (float)(0.5 * (1.0 - DQ / den));
    }
    __syncthreads();
  }
}

// ---------------------------------------------------------------------------
// meta: boundaries, chunk ids, compaction, num_chunks, aux per batch
// ---------------------------------------------------------------------------
__global__ __launch_bounds__(256) void meta_kernel(
    const float* __restrict__ probs, int* __restrict__ cid,
    int* __restrict__ pos, float* __restrict__ cprob,
    int* __restrict__ numC, float* __restrict__ auxv)
{
  __shared__ int   sc[256];
  __shared__ float psh[256];
  int b = blockIdx.x, t = threadIdx.x;
  const float* pr = probs + b * 4096;
  int base = t * 16;
  float pv[16]; int loc[16]; bool bd[16];
  int cnt = 0; float ps = 0.f;
#pragma unroll
  for (int i = 0; i < 16; i++) {
    float p = pr[base + i];
    pv[i] = p; ps += p;
    bool bb = (base + i == 0) || (p > 0.5f);
    bd[i] = bb; cnt += bb ? 1 : 0; loc[i] = cnt;
  }
  sc[t] = cnt; psh[t] = ps;
  __syncthreads();
  for (int off = 1; off < 256; off <<= 1) {
    int add = (t >= off) ? sc[t - off] : 0;
    __syncthreads();
    sc[t] += add;
    __syncthreads();
  }
  int excl = sc[t] - cnt;
#pragma unroll
  for (int i = 0; i < 16; i++) {
    int c = excl + loc[i] - 1;
    cid[b * 4096 + base + i] = c;
    if (bd[i]) { pos[b * 4096 + c] = base + i; cprob[b * 4096 + c] = pv[i]; }
  }
  int total = sc[255];
  for (int off = 128; off > 0; off >>= 1) {
    if (t < off) psh[t] += psh[t + off];
    __syncthreads();
  }
  if (t == 0) {
    numC[b] = total;
    float F = (float)total / 4096.f;
    float G = psh[0] / 4096.f;
    auxv[b] = 1.2f * (5.f * F * G + (1.f - F) * (1.f - G));
  }
}

__global__ void aux_final(const float* __restrict__ auxv, float* __restrict__ out2)
{
  if (threadIdx.x == 0) {
    float s = 0.f;
    for (int i = 0; i < 8; i++) s += auxv[i];
    out2[0] = s * (0.03f / 8.f);
  }
}

__global__ __launch_bounds__(256) void down_kernel(
    const float* __restrict__ tok, const int* __restrict__ pos,
    const float* __restrict__ cprob, const int* __restrict__ numC,
    float* __restrict__ out0)
{
  int blk = blockIdx.x;
  int b = blk >> 12, slot = blk & 4095;
  float4 v = make_float4(0.f, 0.f, 0.f, 0.f);
  if (slot < numC[b]) {
    int l = pos[blk];
    float p = cprob[blk];
    float4 tv = *(const float4*)(tok + (size_t)((b << 12) + l) * 1024 + threadIdx.x * 4);
    v = make_float4(p * tv.x, p * tv.y, p * tv.z, p * tv.w);
  }
  *(float4*)(out0 + (size_t)blk * 1024 + threadIdx.x * 4) = v;
}

// Segmented gated scan, 64-step warm-up (gates < 0.5 => error < 2^-64)
__global__ __launch_bounds__(256) void scanH_kernel(
    const float* __restrict__ out0, const float* __restrict__ cprob,
    const int* __restrict__ numC, float* __restrict__ H)
{
  int seg = blockIdx.x, b = blockIdx.y;
  int nc = numC[b];
  int cs = seg << 8;
  if (cs >= nc) return;
  int ce = min(cs + 256, nc);
  int c0 = (seg == 0) ? 0 : cs - 64;
  int off = threadIdx.x * 4;
  float hx = 0.f, hy = 0.f, hz = 0.f, hw = 0.f;
  int c = c0;
  for (; c < cs; c++) {
    float g = 1.f - cprob[(b << 12) + c];
    float4 xv = *(const float4*)(out0 + (size_t)((b << 12) + c) * 1024 + off);
    hx = fmaf(g, hx, xv.x); hy = fmaf(g, hy, xv.y);
    hz = fmaf(g, hz, xv.z); hw = fmaf(g, hw, xv.w);
  }
  for (; c < ce; c++) {
    float g = 1.f - cprob[(b << 12) + c];
    float4 xv = *(const float4*)(out0 + (size_t)((b << 12) + c) * 1024 + off);
    hx = fmaf(g, hx, xv.x); hy = fmaf(g, hy, xv.y);
    hz = fmaf(g, hz, xv.z); hw = fmaf(g, hw, xv.w);
    *(float4*)(H + (size_t)((b << 12) + c) * 1024 + off) = make_float4(hx, hy, hz, hw);
  }
}

// ---------------------------------------------------------------------------
extern "C" void kernel_launch(void* const* d_in, const int* in_sizes, int n_in,
                              void* d_out, int out_size, void* d_ws, size_t ws_size,
                              hipStream_t stream)
{
  const float* tokens = (const float*)d_in[0];
  const float* Wqk    = (const float*)d_in[1];
  const float* sk     = (const float*)d_in[2];
  const float* Wres   = (const float*)d_in[3];
  const float* bres   = (const float*)d_in[4];

  float* out0 = (float*)d_out;
  float* out1 = out0 + (size_t)M_ * D_;
  float* out2 = out1 + (size_t)M_ * D_;

  char* ws = (char*)d_ws;
  __half* C1h  = (__half*)ws;                          // [32768,2048] fp16 = 134MB
  float*  Hbuf = (float*)ws;                           // aliases C1h (dead after probs)
  u16* Th = (u16*)(ws + 134217728ull);                 // 67MB
  u16* Tl = (u16*)(ws + 201326592ull);                 // 67MB
  u16* Wh = (u16*)(ws + 268435456ull);                 // 4MB (shared qk/res)
  u16* Wl = (u16*)(ws + 272629760ull);                 // 4MB
  float* probs = (float*)(ws + 276824064ull);
  int*   cidp  = (int*)(ws + 276955136ull);
  int*   posp  = (int*)(ws + 277086208ull);
  float* cprob = (float*)(ws + 277217280ull);
  int*   numC  = (int*)(ws + 277348352ull);
  float* auxv  = (float*)(ws + 277348416ull);

  // 1. bf16 hi/lo splits
  split_tok<<<16384, 256, 0, stream>>>(tokens, Th, Tl);
  split_wT<<<1024, 256, 0, stream>>>(Wqk, 2048, Wh, Wl);
  // 2. qk projection: bf16x3 MFMA -> fp16 C1
  gemm_mfma<<<4096, 256, 0, stream>>>(Th, Tl, Wh, Wl, C1h, 2048, 16, 0,
                                      nullptr, nullptr, nullptr);
  // 3. cosine -> probs
  probs_half<<<8192, 256, 0, stream>>>(C1h, sk, probs);
  // 4. fp64 re-check near threshold
  recheck_kernel<<<256, 256, 0, stream>>>(tokens, Wqk, sk, probs);
  // 5. boundaries / chunk ids / compaction / aux
  meta_kernel<<<8, 256, 0, stream>>>(probs, cidp, posp, cprob, numC, auxv);
  aux_final<<<1, 64, 0, stream>>>(auxv, out2);
  // 6. downsampled
  down_kernel<<<M_, 256, 0, stream>>>(tokens, posp, cprob, numC, out0);
  // 7. gated scan -> H (overwrites C1h region)
  scanH_kernel<<<dim3(16, 8), 256, 0, stream>>>(out0, cprob, numC, Hbuf);
  // 8. res splits (reuse W buffers — C1h already consumed)
  split_wT<<<512, 256, 0, stream>>>(Wres, 1024, Wh, Wl);
  // 9. ups = tokens@Wres + H[cid] + bres (bf16x3 MFMA, fused epilogue)
  gemm_mfma<<<2048, 256, 0, stream>>>(Th, Tl, Wh, Wl, out1, 1024, 8, 1,
                                      Hbuf, cidp, bres);
}